// Round 12
// baseline (5234.021 us; speedup 1.0000x reference)
//
#include <hip/hip_runtime.h>
#include <math.h>

// B=128, T=512, D=64, H=512. 256 WGs = 32 dim-slices (16 dims each) x 8 XCD-groups (16 batches).
// 1 WG/CU. Gates via split-bf16 MFMA (3-term), weight B-frags in registers.
// ROUND-12 CHANGE: h image (MFMA-fragment-linear in hist) is read DIRECTLY from global
// (L2-local cached) into registers — no LDS round-trip, no sync A, hp kept in register
// (own previous publish, identical-arithmetic reconstruction). LDS in the loop holds only
// PREP/ORED/XPRE. Mode 0 fallback keeps LDS staging with agent atomic loads.
// Modes: 2 = XCD-local hist (plain-store publish -> local L2; plain-load fetch; strided
// per-WG flag lines, arrival fetch_add(+1), poll fetch_add(+0x10000) RMW, per-lane exit);
// 1 = agent/LLC hist; 0 = agent ring.
#define TB 512
#define NWG 256
#define NSL 32

typedef __attribute__((ext_vector_type(8))) short bf16x8;
typedef __attribute__((ext_vector_type(4))) float f32x4;
typedef unsigned long long u64;

// LDS float offsets. Bytes [0,32768) = B-build scratch at init; mode-0 A-stage in loop.
#define PREP_F 8192      // [2kh][2slot][32 rows][17] = 2176
#define XPRE_F 10368     // 48 x 17 = 816 (teacher x-dot r16,z16,n16)
#define ORED_F 11184     // 2 x 16 x 17 = 544 (out partials, 2 dims)
#define WOC_F  11728     // 2 x 512 (W_out cols 2s, 2s+1)
#define WIH_F  12752     // 48 x 66 = 3168
#define SB_F   15920     // 176 biases ([160..161]=b_out)
#define XLAST_F 16096    // 16
#define MSK_F  16112     // 512 ints
#define ROLE_F 16624     // 4 ints
#define LDS_FLOATS 16640
#define LDS_BYTES (LDS_FLOATS * 4)   // 66560

#define FLAG_STRIDE 32               // one flag word per 128B line
#define FLAGS_BYTES (NWG * 128)      // 32KB
#define REG_OFF FLAGS_BYTES
#define CTRL_BYTES (FLAGS_BYTES + 4096)
#define GRP_BYTES 32768
#define STEP_BYTES (8 * GRP_BYTES)
#define DATA_OFF CTRL_BYTES
#define HIST_NEEDED ((unsigned long long)DATA_OFF + 513ull * STEP_BYTES)
#define FB_NEEDED   ((unsigned long long)DATA_OFF + 2ull * STEP_BYTES)

__device__ __forceinline__ unsigned rne16(float f) {
  unsigned u = __float_as_uint(f);
  return (u + 0x7FFFu + ((u >> 16) & 1u)) >> 16;
}
__device__ __forceinline__ float bfhilo(unsigned hh, unsigned hl) {
  return __uint_as_float(hh << 16) + __uint_as_float(hl << 16);
}

__global__ __launch_bounds__(TB, 2) void gru_persistent(
    const float* __restrict__ x, const float* __restrict__ tp, const int* __restrict__ mask,
    const float* __restrict__ W_ih, const float* __restrict__ W_hh,
    const float* __restrict__ b_ih, const float* __restrict__ b_hh,
    const float* __restrict__ W_out, const float* __restrict__ b_out,
    char* __restrict__ ws, float* __restrict__ out, int hist)
{
  extern __shared__ char smem[];
  float* LP = (float*)smem;
  int* MSK = (int*)&LP[MSK_F];
  volatile int* ROLE = (volatile int*)&LP[ROLE_F];
  const int tid = threadIdx.x;
  const int lane = tid & 63;
  const int wv   = tid >> 6;
  const int myct = wv >> 1, mykh = wv & 1;

  unsigned* flags = (unsigned*)ws;
  unsigned* reg   = (unsigned*)(ws + REG_OFF);
  char* data = ws + DATA_OFF;

  // ---------------- registration: discover XCD placement ----------------
  if (tid == 0) {
    unsigned xcc = 0;
    asm volatile("s_getreg_b32 %0, hwreg(HW_REG_XCC_ID)" : "=s"(xcc));
    xcc &= 7u;
    unsigned rank = __hip_atomic_fetch_add(&reg[xcc], 1u, __ATOMIC_RELAXED, __HIP_MEMORY_SCOPE_AGENT);
    __hip_atomic_fetch_add(&reg[8], 1u, __ATOMIC_RELAXED, __HIP_MEMORY_SCOPE_AGENT);
    int cnt = 0;
    while (__hip_atomic_load(&reg[8], __ATOMIC_RELAXED, __HIP_MEMORY_SCOPE_AGENT) < (unsigned)NWG) {
      __builtin_amdgcn_s_sleep(8);
      if (++cnt > 2000000) break;
    }
    int ok = 1;
    for (int i = 0; i < 8; ++i)
      ok &= (__hip_atomic_load(&reg[i], __ATOMIC_RELAXED, __HIP_MEMORY_SCOPE_AGENT) == (unsigned)NSL);
    ok &= (rank < (unsigned)NSL);
    ROLE[0] = ok ? (int)xcc : (int)(blockIdx.x & 7);
    ROLE[1] = ok ? (int)rank : (int)(blockIdx.x >> 3);
    ROLE[2] = ok;
  }
  __syncthreads();
  const int g = ROLE[0];
  const int s = ROLE[1];          // 0..31
  const int mode = (ROLE[2] && hist) ? 2 : (hist ? 1 : 0);
  const int bg0 = g * 16;
  const int j0  = 16 * s;
  const int ks0 = s >> 1;
  const int c0  = (2 * s) & 3, c1 = (2 * s + 1) & 3;

  // ---------------- init staging ----------------
  MSK[tid] = mask[tid];
  if (tid < 65) {
    for (int p = 0; p < 48; ++p) {
      int row = (p < 16) ? (j0 + p) : (p < 32) ? (512 + j0 + (p - 16)) : (1024 + j0 + (p - 32));
      LP[WIH_F + p * 66 + tid] = W_ih[(size_t)row * 65 + tid];
    }
  }
  LP[WOC_F + tid]       = W_out[(size_t)tid * 64 + 2 * s];
  LP[WOC_F + 512 + tid] = W_out[(size_t)tid * 64 + 2 * s + 1];
  if (tid < 48) {
    int row = (tid < 16) ? (j0 + tid) : (tid < 32) ? (512 + j0 + (tid - 16)) : (1024 + j0 + (tid - 32));
    const float* wi = W_ih + (size_t)row * 65;
    float bp = 0.f;
    for (int d = 0; d < 64; ++d) bp = fmaf(wi[d], b_out[d], bp);
    if (tid < 32) {
      float bt = b_ih[row] + b_hh[row];
      LP[SB_F + tid]      = bt;        // teacher rz bias
      LP[SB_F + 32 + tid] = bt + bp;   // AR rz bias
      LP[SB_F + 64 + tid] = wi[64];    // xlast coef rz
    } else {
      int jj = tid - 32;
      LP[SB_F + 96 + jj]  = b_hh[row];       // nh bias
      LP[SB_F + 112 + jj] = b_ih[row];       // ni teacher
      LP[SB_F + 128 + jj] = b_ih[row] + bp;  // ni AR
      LP[SB_F + 144 + jj] = wi[64];          // xlast coef n
    }
  } else if (tid < 50) {
    LP[SB_F + 160 + (tid - 48)] = b_out[2 * s + (tid - 48)];
  }
  __syncthreads();

  // ---------------- build B-frags to registers: 3 ct x 2 col-halves via 32KB scratch ----------
  bf16x8 Bh[16], Bl[16];
  {
    unsigned short* bw16 = (unsigned short*)smem;
#pragma unroll
    for (int ct = 0; ct < 3; ++ct) {
#pragma unroll
      for (int hc = 0; hc < 2; ++hc) {
        const int k = tid;
        const float* wo = W_out + (size_t)k * 64;
        for (int c16 = 0; c16 < 16; ++c16) {
          const int col = hc * 16 + c16;
          float w;
          if (ct == 0) {
            if (col < 16) w = W_hh[(size_t)(1024 + j0 + col) * 512 + k];   // nh
            else {                                                          // ni: Wc only
              const float* wrp = &LP[WIH_F + (32 + col - 16) * 66];
              float a = 0.f;
#pragma unroll 8
              for (int d = 0; d < 64; ++d) a = fmaf(wrp[d], wo[d], a);
              w = a;
            }
          } else if (ct == 1) {
            int row = (col < 16) ? (j0 + col) : (512 + j0 + col - 16);
            w = W_hh[(size_t)row * 512 + k];
          } else {
            int row = (col < 16) ? (j0 + col) : (512 + j0 + col - 16);
            const float* wrp = &LP[WIH_F + col * 66];   // r rows 0-15, z rows 16-31
            float a = 0.f;
#pragma unroll 8
            for (int d = 0; d < 64; ++d) a = fmaf(wrp[d], wo[d], a);
            w = a + W_hh[(size_t)row * 512 + k];
          }
          unsigned wh_ = rne16(w);
          float resid = w - __uint_as_float(wh_ << 16);
          unsigned wl_ = rne16(resid);
          int base = (k >> 5) * 1024 + (c16 | (((k >> 3) & 3) << 4)) * 16 + (k & 7) * 2;
          bw16[base >> 1] = (unsigned short)wh_;
          bw16[(base + 16384) >> 1] = (unsigned short)wl_;
        }
        __syncthreads();
        if (wv < 6 && myct == ct) {
#pragma unroll
          for (int i = 0; i < 8; ++i) {
            Bh[hc * 8 + i] = *(const bf16x8*)(smem + (mykh * 8 + i) * 1024 + lane * 16);
            Bl[hc * 8 + i] = *(const bf16x8*)(smem + 16384 + (mykh * 8 + i) * 1024 + lane * 16);
          }
        }
        __syncthreads();
      }
    }
  }

  // ---------------- zero h0 (buffer 0): this WG's publish region ----------------
  if (tid < 32) {
    const int b = tid & 15, term = tid >> 4;
    char* dst = data + (size_t)g * GRP_BYTES + (size_t)(term * 16 + ks0) * 1024;
    u64* p0 = (u64*)(dst + (size_t)(b | (c0 << 4)) * 16);
    u64* p1 = (u64*)(dst + (size_t)(b | (c1 << 4)) * 16);
    if (mode == 2) {
      *(volatile u64*)p0 = 0ull; *(volatile u64*)(p0 + 1) = 0ull;
      *(volatile u64*)p1 = 0ull; *(volatile u64*)(p1 + 1) = 0ull;
    } else {
      __hip_atomic_store(p0,     0ull, __ATOMIC_RELAXED, __HIP_MEMORY_SCOPE_AGENT);
      __hip_atomic_store(p0 + 1, 0ull, __ATOMIC_RELAXED, __HIP_MEMORY_SCOPE_AGENT);
      __hip_atomic_store(p1,     0ull, __ATOMIC_RELAXED, __HIP_MEMORY_SCOPE_AGENT);
      __hip_atomic_store(p1 + 1, 0ull, __ATOMIC_RELAXED, __HIP_MEMORY_SCOPE_AGENT);
    }
  }

  // teacher x-dot staging for step tt (h-independent; runs in barrier windows)
  auto stage_x = [&](int tt) {
    if (tt >= 512) return;
    if (MSK[tt] != 0) {
      for (int task = tid; task < 768; task += TB) {
        const int xr = task >> 4, b = task & 15;
        const float* wrow = &LP[WIH_F + xr * 66];
        size_t ti = (size_t)(bg0 + b) * 512 + tt;
        float del = tp[ti] - (tt > 0 ? tp[ti - 1] : 0.f);
        float xa = wrow[64] * del;
        const float4* x4 = (const float4*)(x + ti * 64);
#pragma unroll
        for (int d4 = 0; d4 < 16; ++d4) {
          float4 xv = x4[d4];
          xa = fmaf(wrow[d4 * 4 + 0], xv.x, xa);
          xa = fmaf(wrow[d4 * 4 + 1], xv.y, xa);
          xa = fmaf(wrow[d4 * 4 + 2], xv.z, xa);
          xa = fmaf(wrow[d4 * 4 + 3], xv.w, xa);
        }
        LP[XPRE_F + xr * 17 + b] = xa;
      }
    } else if (tid < 16) {
      LP[XLAST_F + tid] = x[((size_t)(bg0 + tid) * 512 + tt) * 64 + 63];
    }
  };

  auto flag_addr = [&](int i) -> unsigned* { return &flags[(size_t)((g << 5) + i) * FLAG_STRIDE]; };
  auto flag_put = [&](unsigned tgt_epoch) {
    if (mode == 2)
      __hip_atomic_fetch_add(flag_addr(s), 1u, __ATOMIC_RELAXED, __HIP_MEMORY_SCOPE_WORKGROUP);
    else
      __hip_atomic_store(flag_addr(s), tgt_epoch, __ATOMIC_RELAXED, __HIP_MEMORY_SCOPE_AGENT);
  };
  // Per-lane-exit poll (round-11-proven): lanes 0..31 each watch one producer.
  auto flag_poll = [&](unsigned tgt_epoch) {
    if (lane < NSL) {
      int cnt = 0;
      while (true) {
        unsigned v;
        if (mode == 2)
          v = __hip_atomic_fetch_add(flag_addr(lane), 0x10000u, __ATOMIC_RELAXED,
                                     __HIP_MEMORY_SCOPE_WORKGROUP) & 0xFFFFu;
        else
          v = __hip_atomic_load(flag_addr(lane), __ATOMIC_RELAXED, __HIP_MEMORY_SCOPE_AGENT);
        if (v >= tgt_epoch) break;
        __builtin_amdgcn_s_sleep(1);
        if (++cnt > 300000) break;   // escape hatch: wrong answer instead of hang
      }
    }
  };

  stage_x(0);
  asm volatile("s_waitcnt vmcnt(0)" ::: "memory");
  __syncthreads();
  if (tid == 0) flag_put(1u);
  if (wv == 7) flag_poll(1u);
  __syncthreads();

  float hpreg = 0.f;   // gate threads: own h(t) value (identical-arithmetic reconstruction)

  for (int t = 0; t <= 512; ++t) {
    const bool last = (t == 512);
    const bool teacher = (!last) && (MSK[t] != 0);
    const int csel = teacher ? 1 : 2;
    const char* src = data + (size_t)(hist ? t : (t & 1)) * STEP_BYTES + (size_t)g * GRP_BYTES;

    // -------- mode 0 only: stage h image to LDS via agent atomic loads --------
    if (mode == 0) {
      u64 a0[4], a1[4];
#pragma unroll
      for (int i = 0; i < 4; ++i) {
        const u64* p = (const u64*)(src + (size_t)(i * 512 + tid) * 16);
        a0[i] = __hip_atomic_load(p,     __ATOMIC_RELAXED, __HIP_MEMORY_SCOPE_AGENT);
        a1[i] = __hip_atomic_load(p + 1, __ATOMIC_RELAXED, __HIP_MEMORY_SCOPE_AGENT);
      }
#pragma unroll
      for (int i = 0; i < 4; ++i) {
        u64* d = (u64*)(smem + (size_t)(i * 512 + tid) * 16);
        d[0] = a0[i]; d[1] = a1[i];
      }
      __syncthreads();
    }
    const char* ab = (mode == 0) ? (const char*)smem : src;

    // -------- MFMA (waves 0-5): A-frags direct global->reg; ct0 always, ct1/ct2 by mode --------
    if (!last && wv < 6 && (myct == 0 || myct == csel)) {
      bf16x8 Ah[8], Al[8];
#pragma unroll
      for (int i = 0; i < 8; ++i) {
        Ah[i] = *(const bf16x8*)(ab + (size_t)((mykh * 8 + i) * 1024) + lane * 16);
        Al[i] = *(const bf16x8*)(ab + 16384 + (size_t)((mykh * 8 + i) * 1024) + lane * 16);
      }
      const int slot = (myct == 0) ? 0 : 1;
#pragma unroll
      for (int ti = 0; ti < 2; ++ti) {
        f32x4 acc0 = {0.f, 0.f, 0.f, 0.f};
        f32x4 acc1 = {0.f, 0.f, 0.f, 0.f};
        f32x4 acc2 = {0.f, 0.f, 0.f, 0.f};
        f32x4 acc3 = {0.f, 0.f, 0.f, 0.f};
#pragma unroll
        for (int i = 0; i < 8; ++i) {
          f32x4& acc = ((i & 3) == 0) ? acc0 : ((i & 3) == 1) ? acc1 : ((i & 3) == 2) ? acc2 : acc3;
          acc = __builtin_amdgcn_mfma_f32_16x16x32_bf16(Ah[i], Bh[ti * 8 + i], acc, 0, 0, 0);
          acc = __builtin_amdgcn_mfma_f32_16x16x32_bf16(Ah[i], Bl[ti * 8 + i], acc, 0, 0, 0);
          acc = __builtin_amdgcn_mfma_f32_16x16x32_bf16(Al[i], Bh[ti * 8 + i], acc, 0, 0, 0);
        }
        f32x4 acc = (acc0 + acc1) + (acc2 + acc3);
        const int row = ti * 16 + (lane & 15);
        const int bcol = (lane >> 4) << 2;
#pragma unroll
        for (int q = 0; q < 4; ++q)
          LP[PREP_F + ((mykh * 2 + slot) * 32 + row) * 17 + bcol + q] = acc[q];
      }
    }

    // -------- out-dot (waves 6,7): direct global reads; 512 tasks, 4/thread --------
    if (wv >= 6) {
#pragma unroll
      for (int tk = 0; tk < 4; ++tk) {
        const int task = (tid - 384) + tk * 128;
        const int d = task >> 8, rem = task & 255;
        const int b = rem & 15, ks = rem >> 4;
        const float* woc = &LP[WOC_F + d * 512];
        float oa = 0.f;
#pragma unroll
        for (int c = 0; c < 4; ++c) {
          const uint4 wh = *(const uint4*)(ab + (size_t)(ks * 1024) + (b | (c << 4)) * 16);
          const uint4 wl = *(const uint4*)(ab + (size_t)(16384 + ks * 1024) + (b | (c << 4)) * 16);
          int k0 = ks * 32 + c * 8;
          oa = fmaf(bfhilo(wh.x & 0xFFFFu, wl.x & 0xFFFFu), woc[k0 + 0], oa);
          oa = fmaf(bfhilo(wh.x >> 16, wl.x >> 16), woc[k0 + 1], oa);
          oa = fmaf(bfhilo(wh.y & 0xFFFFu, wl.y & 0xFFFFu), woc[k0 + 2], oa);
          oa = fmaf(bfhilo(wh.y >> 16, wl.y >> 16), woc[k0 + 3], oa);
          oa = fmaf(bfhilo(wh.z & 0xFFFFu, wl.z & 0xFFFFu), woc[k0 + 4], oa);
          oa = fmaf(bfhilo(wh.z >> 16, wl.z >> 16), woc[k0 + 5], oa);
          oa = fmaf(bfhilo(wh.w & 0xFFFFu, wl.w & 0xFFFFu), woc[k0 + 6], oa);
          oa = fmaf(bfhilo(wh.w >> 16, wl.w >> 16), woc[k0 + 7], oa);
        }
        LP[ORED_F + d * 272 + b * 17 + ks] = oa;
      }
    }
    __syncthreads();   // sync B

    if (!last) {
      // -------- gates (tid<256: b=tid&15, jj=tid>>4) -> shfl pack -> publish --------
      if (tid < 256) {
        const int b = tid & 15, jj = tid >> 4;
        const float* PR = &LP[PREP_F];
        float pr  = PR[(1 * 32 + jj) * 17 + b]      + PR[(3 * 32 + jj) * 17 + b];
        float pz  = PR[(1 * 32 + 16 + jj) * 17 + b] + PR[(3 * 32 + 16 + jj) * 17 + b];
        float pnh = PR[(0 * 32 + jj) * 17 + b]      + PR[(2 * 32 + jj) * 17 + b]
                  + LP[SB_F + 96 + jj];
        float pni;
        if (teacher) {
          pr += LP[XPRE_F + jj * 17 + b] + LP[SB_F + jj];
          pz += LP[XPRE_F + (16 + jj) * 17 + b] + LP[SB_F + 16 + jj];
          pni = LP[XPRE_F + (32 + jj) * 17 + b] + LP[SB_F + 112 + jj];
        } else {
          float xl = LP[XLAST_F + b];
          pr += LP[SB_F + 32 + jj] + LP[SB_F + 64 + jj] * xl;
          pz += LP[SB_F + 48 + jj] + LP[SB_F + 80 + jj] * xl;
          pni = PR[(0 * 32 + 16 + jj) * 17 + b] + PR[(2 * 32 + 16 + jj) * 17 + b]
              + LP[SB_F + 128 + jj] + LP[SB_F + 144 + jj] * xl;
        }
        float rg = 1.f / (1.f + expf(-pr));
        float zg = 1.f / (1.f + expf(-pz));
        float ng = tanhf(fmaf(rg, pnh, pni));
        float hv = fmaf(zg, hpreg - ng, ng);
        // reconstruct own published value (same arithmetic the partner pack uses)
        unsigned h0h = rne16(hv);
        float r0 = hv - __uint_as_float(h0h << 16);
        unsigned l0w = rne16(r0);
        hpreg = __uint_as_float(h0h << 16) + __uint_as_float(l0w << 16);
        float hvp = __shfl_xor(hv, 16, 64);   // partner jj^1, same batch
        if ((jj & 1) == 0) {
          unsigned h1h = rne16(hvp);
          float r1 = hvp - __uint_as_float(h1h << 16);
          unsigned hw = h0h | (h1h << 16);
          unsigned lw = l0w | (rne16(r1) << 16);
          const int cc = (2 * s + (jj >> 3)) & 3;
          const int e = jj & 7;
          size_t hoff = (size_t)ks0 * 1024 + (size_t)(b | (cc << 4)) * 16 + (size_t)e * 2;
          char* dst = data + (size_t)(hist ? (t + 1) : ((t + 1) & 1)) * STEP_BYTES
                    + (size_t)g * GRP_BYTES;
          unsigned* dhh = (unsigned*)(dst + hoff);
          unsigned* dhl = (unsigned*)(dst + 16384 + hoff);
          if (mode == 2) {
            *(volatile unsigned*)dhh = hw;
            *(volatile unsigned*)dhl = lw;
          } else {
            __hip_atomic_store(dhh, hw, __ATOMIC_RELAXED, __HIP_MEMORY_SCOPE_AGENT);
            __hip_atomic_store(dhl, lw, __ATOMIC_RELAXED, __HIP_MEMORY_SCOPE_AGENT);
          }
        }
      }
      // -------- barrier: drain, arrive, hidden work, poll (per-lane exit), release --------
      asm volatile("s_waitcnt vmcnt(0)" ::: "memory");
      __syncthreads();   // sync C
      const unsigned tgt = (unsigned)(t + 2);
      if (tid == 0) flag_put(tgt);
      if (t >= 1 && tid >= 256 && tid < 288) {
        const int q = tid - 256, b = q & 15, d = q >> 4;
        float o = LP[SB_F + 160 + d];
#pragma unroll
        for (int i = 0; i < 16; ++i) o += LP[ORED_F + d * 272 + b * 17 + i];
        out[((size_t)(bg0 + b) * 512 + (t - 1)) * 64 + 2 * s + d] = o;
      }
      stage_x(t + 1);
      if (wv == 7) flag_poll(tgt);
      __syncthreads();   // sync D
    } else {
      if (tid >= 256 && tid < 288) {
        const int q = tid - 256, b = q & 15, d = q >> 4;
        float o = LP[SB_F + 160 + d];
#pragma unroll
        for (int i = 0; i < 16; ++i) o += LP[ORED_F + d * 272 + b * 17 + i];
        out[((size_t)(bg0 + b) * 512 + 511) * 64 + 2 * s + d] = o;
      }
    }
  }
}

extern "C" void kernel_launch(void* const* d_in, const int* in_sizes, int n_in,
                              void* d_out, int out_size, void* d_ws, size_t ws_size,
                              hipStream_t stream) {
  (void)in_sizes; (void)n_in; (void)out_size;
  const float* x    = (const float*)d_in[0];
  const float* tp   = (const float*)d_in[1];
  const int*   mask = (const int*)d_in[2];
  const float* W_ih = (const float*)d_in[3];
  const float* W_hh = (const float*)d_in[4];
  const float* b_ih = (const float*)d_in[5];
  const float* b_hh = (const float*)d_in[6];
  const float* W_out= (const float*)d_in[7];
  const float* b_out= (const float*)d_in[8];
  float* out = (float*)d_out;
  if (ws_size < FB_NEEDED) return;
  int hist = (ws_size >= HIST_NEEDED) ? 1 : 0;
  hipMemsetAsync(d_ws, 0, CTRL_BYTES, stream);
  hipFuncSetAttribute((const void*)gru_persistent,
                      hipFuncAttributeMaxDynamicSharedMemorySize, LDS_BYTES);
  hipLaunchKernelGGL(gru_persistent, dim3(NWG), dim3(TB), LDS_BYTES, stream,
                     x, tp, mask, W_ih, W_hh, b_ih, b_hh, W_out, b_out,
                     (char*)d_ws, out, hist);
}

// Round 13
// 3589.845 us; speedup vs baseline: 1.4580x; 1.4580x over previous
//
#include <hip/hip_runtime.h>
#include <math.h>

// B=128, T=512, D=64, H=512. 256 WGs = 32 dim-slices (16 dims each) x 8 XCD-groups (16 batches).
// 1 WG/CU. Round-11 structure (best: 3598us) + two chain cuts:
//  (1) hpreg: gates keep own h in register (round-12-proven) — no image read in gate phase.
//  (2) per-wave aligned poll+stage: wave wv stages image chunks sg={wv,8+wv,16+wv,24+wv},
//      which depend on exactly producers {2wv,2wv+1,16+2wv,17+2wv}; each wave polls only
//      those 4 flags (4 lanes) then stages its 4KB. Removes sync D; 3 syncs/step.
// Modes: 2 = XCD-local hist (plain-store publish -> local L2; plain-load fetch; strided
// per-WG flag lines, arrival fetch_add(+1), poll fetch_add(+0x10000)&0xFFFF, per-lane exit);
// 1 = agent/LLC hist; 0 = agent ring.
#define TB 512
#define NWG 256
#define NSL 32

typedef __attribute__((ext_vector_type(8))) short bf16x8;
typedef __attribute__((ext_vector_type(4))) float f32x4;
typedef unsigned long long u64;

// LDS float offsets. Bytes [0,32768) = staged h image (and B-build scratch at init).
#define PREP_F 8192      // [2kh][2slot][32 rows][17] = 2176
#define XPRE_F 10368     // 48 x 17 = 816 (teacher x-dot r16,z16,n16)
#define ORED_F 11184     // 2 x 16 x 17 = 544 (out partials, 2 dims)
#define WOC_F  11728     // 2 x 512 (W_out cols 2s, 2s+1)
#define WIH_F  12752     // 48 x 66 = 3168
#define SB_F   15920     // 176 biases ([160..161]=b_out)
#define XLAST_F 16096    // 16
#define MSK_F  16112     // 512 ints
#define ROLE_F 16624     // 4 ints
#define LDS_FLOATS 16640
#define LDS_BYTES (LDS_FLOATS * 4)   // 66560

#define FLAG_STRIDE 32               // one flag word per 128B line
#define FLAGS_BYTES (NWG * 128)      // 32KB
#define REG_OFF FLAGS_BYTES
#define CTRL_BYTES (FLAGS_BYTES + 4096)
#define GRP_BYTES 32768
#define STEP_BYTES (8 * GRP_BYTES)
#define DATA_OFF CTRL_BYTES
#define HIST_NEEDED ((unsigned long long)DATA_OFF + 513ull * STEP_BYTES)
#define FB_NEEDED   ((unsigned long long)DATA_OFF + 2ull * STEP_BYTES)

__device__ __forceinline__ unsigned rne16(float f) {
  unsigned u = __float_as_uint(f);
  return (u + 0x7FFFu + ((u >> 16) & 1u)) >> 16;
}
__device__ __forceinline__ float bfhilo(unsigned hh, unsigned hl) {
  return __uint_as_float(hh << 16) + __uint_as_float(hl << 16);
}

__global__ __launch_bounds__(TB, 2) void gru_persistent(
    const float* __restrict__ x, const float* __restrict__ tp, const int* __restrict__ mask,
    const float* __restrict__ W_ih, const float* __restrict__ W_hh,
    const float* __restrict__ b_ih, const float* __restrict__ b_hh,
    const float* __restrict__ W_out, const float* __restrict__ b_out,
    char* __restrict__ ws, float* __restrict__ out, int hist)
{
  extern __shared__ char smem[];
  float* LP = (float*)smem;
  int* MSK = (int*)&LP[MSK_F];
  volatile int* ROLE = (volatile int*)&LP[ROLE_F];
  const int tid = threadIdx.x;
  const int lane = tid & 63;
  const int wv   = tid >> 6;
  const int myct = wv >> 1, mykh = wv & 1;

  unsigned* flags = (unsigned*)ws;
  unsigned* reg   = (unsigned*)(ws + REG_OFF);
  char* data = ws + DATA_OFF;

  // ---------------- registration: discover XCD placement ----------------
  if (tid == 0) {
    unsigned xcc = 0;
    asm volatile("s_getreg_b32 %0, hwreg(HW_REG_XCC_ID)" : "=s"(xcc));
    xcc &= 7u;
    unsigned rank = __hip_atomic_fetch_add(&reg[xcc], 1u, __ATOMIC_RELAXED, __HIP_MEMORY_SCOPE_AGENT);
    __hip_atomic_fetch_add(&reg[8], 1u, __ATOMIC_RELAXED, __HIP_MEMORY_SCOPE_AGENT);
    int cnt = 0;
    while (__hip_atomic_load(&reg[8], __ATOMIC_RELAXED, __HIP_MEMORY_SCOPE_AGENT) < (unsigned)NWG) {
      __builtin_amdgcn_s_sleep(8);
      if (++cnt > 2000000) break;
    }
    int ok = 1;
    for (int i = 0; i < 8; ++i)
      ok &= (__hip_atomic_load(&reg[i], __ATOMIC_RELAXED, __HIP_MEMORY_SCOPE_AGENT) == (unsigned)NSL);
    ok &= (rank < (unsigned)NSL);
    ROLE[0] = ok ? (int)xcc : (int)(blockIdx.x & 7);
    ROLE[1] = ok ? (int)rank : (int)(blockIdx.x >> 3);
    ROLE[2] = ok;
  }
  __syncthreads();
  const int g = ROLE[0];
  const int s = ROLE[1];          // 0..31
  const int mode = (ROLE[2] && hist) ? 2 : (hist ? 1 : 0);
  const int bg0 = g * 16;
  const int j0  = 16 * s;
  const int ks0 = s >> 1;
  const int c0  = (2 * s) & 3, c1 = (2 * s + 1) & 3;

  // ---------------- init staging ----------------
  MSK[tid] = mask[tid];
  if (tid < 65) {
    for (int p = 0; p < 48; ++p) {
      int row = (p < 16) ? (j0 + p) : (p < 32) ? (512 + j0 + (p - 16)) : (1024 + j0 + (p - 32));
      LP[WIH_F + p * 66 + tid] = W_ih[(size_t)row * 65 + tid];
    }
  }
  LP[WOC_F + tid]       = W_out[(size_t)tid * 64 + 2 * s];
  LP[WOC_F + 512 + tid] = W_out[(size_t)tid * 64 + 2 * s + 1];
  if (tid < 48) {
    int row = (tid < 16) ? (j0 + tid) : (tid < 32) ? (512 + j0 + (tid - 16)) : (1024 + j0 + (tid - 32));
    const float* wi = W_ih + (size_t)row * 65;
    float bp = 0.f;
    for (int d = 0; d < 64; ++d) bp = fmaf(wi[d], b_out[d], bp);
    if (tid < 32) {
      float bt = b_ih[row] + b_hh[row];
      LP[SB_F + tid]      = bt;        // teacher rz bias
      LP[SB_F + 32 + tid] = bt + bp;   // AR rz bias
      LP[SB_F + 64 + tid] = wi[64];    // xlast coef rz
    } else {
      int jj = tid - 32;
      LP[SB_F + 96 + jj]  = b_hh[row];       // nh bias
      LP[SB_F + 112 + jj] = b_ih[row];       // ni teacher
      LP[SB_F + 128 + jj] = b_ih[row] + bp;  // ni AR
      LP[SB_F + 144 + jj] = wi[64];          // xlast coef n
    }
  } else if (tid < 50) {
    LP[SB_F + 160 + (tid - 48)] = b_out[2 * s + (tid - 48)];
  }
  __syncthreads();

  // ---------------- build B-frags to registers: 3 ct x 2 col-halves via 32KB scratch ----------
  bf16x8 Bh[16], Bl[16];
  {
    unsigned short* bw16 = (unsigned short*)smem;
#pragma unroll
    for (int ct = 0; ct < 3; ++ct) {
#pragma unroll
      for (int hc = 0; hc < 2; ++hc) {
        const int k = tid;
        const float* wo = W_out + (size_t)k * 64;
        for (int c16 = 0; c16 < 16; ++c16) {
          const int col = hc * 16 + c16;
          float w;
          if (ct == 0) {
            if (col < 16) w = W_hh[(size_t)(1024 + j0 + col) * 512 + k];   // nh
            else {                                                          // ni: Wc only
              const float* wrp = &LP[WIH_F + (32 + col - 16) * 66];
              float a = 0.f;
#pragma unroll 8
              for (int d = 0; d < 64; ++d) a = fmaf(wrp[d], wo[d], a);
              w = a;
            }
          } else if (ct == 1) {
            int row = (col < 16) ? (j0 + col) : (512 + j0 + col - 16);
            w = W_hh[(size_t)row * 512 + k];
          } else {
            int row = (col < 16) ? (j0 + col) : (512 + j0 + col - 16);
            const float* wrp = &LP[WIH_F + col * 66];   // r rows 0-15, z rows 16-31
            float a = 0.f;
#pragma unroll 8
            for (int d = 0; d < 64; ++d) a = fmaf(wrp[d], wo[d], a);
            w = a + W_hh[(size_t)row * 512 + k];
          }
          unsigned wh_ = rne16(w);
          float resid = w - __uint_as_float(wh_ << 16);
          unsigned wl_ = rne16(resid);
          int base = (k >> 5) * 1024 + (c16 | (((k >> 3) & 3) << 4)) * 16 + (k & 7) * 2;
          bw16[base >> 1] = (unsigned short)wh_;
          bw16[(base + 16384) >> 1] = (unsigned short)wl_;
        }
        __syncthreads();
        if (wv < 6 && myct == ct) {
#pragma unroll
          for (int i = 0; i < 8; ++i) {
            Bh[hc * 8 + i] = *(const bf16x8*)(smem + (mykh * 8 + i) * 1024 + lane * 16);
            Bl[hc * 8 + i] = *(const bf16x8*)(smem + 16384 + (mykh * 8 + i) * 1024 + lane * 16);
          }
        }
        __syncthreads();
      }
    }
  }

  // ---------------- zero h0 (buffer 0): this WG's publish region ----------------
  if (tid < 32) {
    const int b = tid & 15, term = tid >> 4;
    char* dst = data + (size_t)g * GRP_BYTES + (size_t)(term * 16 + ks0) * 1024;
    u64* p0 = (u64*)(dst + (size_t)(b | (c0 << 4)) * 16);
    u64* p1 = (u64*)(dst + (size_t)(b | (c1 << 4)) * 16);
    if (mode == 2) {
      *(volatile u64*)p0 = 0ull; *(volatile u64*)(p0 + 1) = 0ull;
      *(volatile u64*)p1 = 0ull; *(volatile u64*)(p1 + 1) = 0ull;
    } else {
      __hip_atomic_store(p0,     0ull, __ATOMIC_RELAXED, __HIP_MEMORY_SCOPE_AGENT);
      __hip_atomic_store(p0 + 1, 0ull, __ATOMIC_RELAXED, __HIP_MEMORY_SCOPE_AGENT);
      __hip_atomic_store(p1,     0ull, __ATOMIC_RELAXED, __HIP_MEMORY_SCOPE_AGENT);
      __hip_atomic_store(p1 + 1, 0ull, __ATOMIC_RELAXED, __HIP_MEMORY_SCOPE_AGENT);
    }
  }

  // teacher x-dot staging for step tt (h-independent; runs in barrier windows)
  auto stage_x = [&](int tt) {
    if (tt >= 512) return;
    if (MSK[tt] != 0) {
      for (int task = tid; task < 768; task += TB) {
        const int xr = task >> 4, b = task & 15;
        const float* wrow = &LP[WIH_F + xr * 66];
        size_t ti = (size_t)(bg0 + b) * 512 + tt;
        float del = tp[ti] - (tt > 0 ? tp[ti - 1] : 0.f);
        float xa = wrow[64] * del;
        const float4* x4 = (const float4*)(x + ti * 64);
#pragma unroll
        for (int d4 = 0; d4 < 16; ++d4) {
          float4 xv = x4[d4];
          xa = fmaf(wrow[d4 * 4 + 0], xv.x, xa);
          xa = fmaf(wrow[d4 * 4 + 1], xv.y, xa);
          xa = fmaf(wrow[d4 * 4 + 2], xv.z, xa);
          xa = fmaf(wrow[d4 * 4 + 3], xv.w, xa);
        }
        LP[XPRE_F + xr * 17 + b] = xa;
      }
    } else if (tid < 16) {
      LP[XLAST_F + tid] = x[((size_t)(bg0 + tid) * 512 + tt) * 64 + 63];
    }
  };

  auto flag_addr = [&](int i) -> unsigned* { return &flags[(size_t)((g << 5) + i) * FLAG_STRIDE]; };
  auto flag_put = [&](unsigned tgt_epoch) {
    if (mode == 2)
      __hip_atomic_fetch_add(flag_addr(s), 1u, __ATOMIC_RELAXED, __HIP_MEMORY_SCOPE_WORKGROUP);
    else
      __hip_atomic_store(flag_addr(s), tgt_epoch, __ATOMIC_RELAXED, __HIP_MEMORY_SCOPE_AGENT);
  };
  // Per-wave poll of THIS WAVE's 4 producers (lanes 0-3 active, per-lane exit), then stage
  // this wave's 4 image chunks. Producers for wave wv: {2wv, 2wv+1, 16+2wv, 17+2wv}.
  auto wave_poll_stage = [&](int tt) {
    const unsigned tgt = (unsigned)(tt + 1);
    if (lane < 4) {
      const int prod = ((lane >> 1) << 4) + 2 * wv + (lane & 1);
      int cnt = 0;
      while (true) {
        unsigned v;
        if (mode == 2)
          v = __hip_atomic_fetch_add(flag_addr(prod), 0x10000u, __ATOMIC_RELAXED,
                                     __HIP_MEMORY_SCOPE_WORKGROUP) & 0xFFFFu;
        else
          v = __hip_atomic_load(flag_addr(prod), __ATOMIC_RELAXED, __HIP_MEMORY_SCOPE_AGENT);
        if (v >= tgt) break;
        __builtin_amdgcn_s_sleep(1);
        if (++cnt > 300000) break;   // escape hatch: wrong answer instead of hang
      }
    }
    const char* src = data + (size_t)(hist ? tt : (tt & 1)) * STEP_BYTES + (size_t)g * GRP_BYTES;
    if (mode == 0) {
      u64 a0[4], a1[4];
#pragma unroll
      for (int i = 0; i < 4; ++i) {
        const u64* p = (const u64*)(src + (size_t)((i * 8 + wv) * 1024) + lane * 16);
        a0[i] = __hip_atomic_load(p,     __ATOMIC_RELAXED, __HIP_MEMORY_SCOPE_AGENT);
        a1[i] = __hip_atomic_load(p + 1, __ATOMIC_RELAXED, __HIP_MEMORY_SCOPE_AGENT);
      }
#pragma unroll
      for (int i = 0; i < 4; ++i) {
        u64* d = (u64*)(smem + (size_t)((i * 8 + wv) * 1024) + lane * 16);
        d[0] = a0[i]; d[1] = a1[i];
      }
    } else {
      uint4 v[4];
#pragma unroll
      for (int i = 0; i < 4; ++i)
        v[i] = *(const uint4*)(src + (size_t)((i * 8 + wv) * 1024) + lane * 16);
#pragma unroll
      for (int i = 0; i < 4; ++i)
        *(uint4*)(smem + (size_t)((i * 8 + wv) * 1024) + lane * 16) = v[i];
    }
  };

  stage_x(0);
  asm volatile("s_waitcnt vmcnt(0)" ::: "memory");
  __syncthreads();
  if (tid == 0) flag_put(1u);

  float hpreg = 0.f;   // gate threads: own h(t) value (identical-arithmetic reconstruction)

  for (int t = 0; t <= 512; ++t) {
    const bool last = (t == 512);
    const bool teacher = (!last) && (MSK[t] != 0);
    const int csel = teacher ? 1 : 2;

    // -------- per-wave: poll my 4 producers for h(t), stage my 4KB of the image --------
    wave_poll_stage(t);
    __syncthreads();   // sync A: full image staged

    // -------- MFMA (waves 0-5): ct0 always, ct1 teacher, ct2 AR; 2 col-tiles each --------
    if (!last && wv < 6 && (myct == 0 || myct == csel)) {
      const int slot = (myct == 0) ? 0 : 1;
#pragma unroll
      for (int ti = 0; ti < 2; ++ti) {
        f32x4 acc0 = {0.f, 0.f, 0.f, 0.f};
        f32x4 acc1 = {0.f, 0.f, 0.f, 0.f};
        f32x4 acc2 = {0.f, 0.f, 0.f, 0.f};
        f32x4 acc3 = {0.f, 0.f, 0.f, 0.f};
#pragma unroll
        for (int i = 0; i < 8; ++i) {
          const char* abh = smem + (size_t)((mykh * 8 + i) * 1024) + lane * 16;
          bf16x8 ahh = *(const bf16x8*)abh;
          bf16x8 ahl = *(const bf16x8*)(abh + 16384);
          f32x4& acc = ((i & 3) == 0) ? acc0 : ((i & 3) == 1) ? acc1 : ((i & 3) == 2) ? acc2 : acc3;
          acc = __builtin_amdgcn_mfma_f32_16x16x32_bf16(ahh, Bh[ti * 8 + i], acc, 0, 0, 0);
          acc = __builtin_amdgcn_mfma_f32_16x16x32_bf16(ahh, Bl[ti * 8 + i], acc, 0, 0, 0);
          acc = __builtin_amdgcn_mfma_f32_16x16x32_bf16(ahl, Bh[ti * 8 + i], acc, 0, 0, 0);
        }
        f32x4 acc = (acc0 + acc1) + (acc2 + acc3);
        const int row = ti * 16 + (lane & 15);
        const int bcol = (lane >> 4) << 2;
#pragma unroll
        for (int q = 0; q < 4; ++q)
          LP[PREP_F + ((mykh * 2 + slot) * 32 + row) * 17 + bcol + q] = acc[q];
      }
    }

    // -------- out-dot (waves 6,7): 512 tasks = 2 dims x 16 b x 16 ks, 4/thread --------
    if (wv >= 6) {
#pragma unroll
      for (int tk = 0; tk < 4; ++tk) {
        const int task = (tid - 384) + tk * 128;
        const int d = task >> 8, rem = task & 255;
        const int b = rem & 15, ks = rem >> 4;
        const float* woc = &LP[WOC_F + d * 512];
        float oa = 0.f;
#pragma unroll
        for (int c = 0; c < 4; ++c) {
          const uint4 wh = *(const uint4*)(smem + (size_t)(ks * 1024) + (b | (c << 4)) * 16);
          const uint4 wl = *(const uint4*)(smem + (size_t)(16384 + ks * 1024) + (b | (c << 4)) * 16);
          int k0 = ks * 32 + c * 8;
          oa = fmaf(bfhilo(wh.x & 0xFFFFu, wl.x & 0xFFFFu), woc[k0 + 0], oa);
          oa = fmaf(bfhilo(wh.x >> 16, wl.x >> 16), woc[k0 + 1], oa);
          oa = fmaf(bfhilo(wh.y & 0xFFFFu, wl.y & 0xFFFFu), woc[k0 + 2], oa);
          oa = fmaf(bfhilo(wh.y >> 16, wl.y >> 16), woc[k0 + 3], oa);
          oa = fmaf(bfhilo(wh.z & 0xFFFFu, wl.z & 0xFFFFu), woc[k0 + 4], oa);
          oa = fmaf(bfhilo(wh.z >> 16, wl.z >> 16), woc[k0 + 5], oa);
          oa = fmaf(bfhilo(wh.w & 0xFFFFu, wl.w & 0xFFFFu), woc[k0 + 6], oa);
          oa = fmaf(bfhilo(wh.w >> 16, wl.w >> 16), woc[k0 + 7], oa);
        }
        LP[ORED_F + d * 272 + b * 17 + ks] = oa;
      }
    }
    __syncthreads();   // sync B

    if (!last) {
      // -------- gates (tid<256: b=tid&15, jj=tid>>4) -> shfl pack -> publish --------
      if (tid < 256) {
        const int b = tid & 15, jj = tid >> 4;
        const float* PR = &LP[PREP_F];
        float pr  = PR[(1 * 32 + jj) * 17 + b]      + PR[(3 * 32 + jj) * 17 + b];
        float pz  = PR[(1 * 32 + 16 + jj) * 17 + b] + PR[(3 * 32 + 16 + jj) * 17 + b];
        float pnh = PR[(0 * 32 + jj) * 17 + b]      + PR[(2 * 32 + jj) * 17 + b]
                  + LP[SB_F + 96 + jj];
        float pni;
        if (teacher) {
          pr += LP[XPRE_F + jj * 17 + b] + LP[SB_F + jj];
          pz += LP[XPRE_F + (16 + jj) * 17 + b] + LP[SB_F + 16 + jj];
          pni = LP[XPRE_F + (32 + jj) * 17 + b] + LP[SB_F + 112 + jj];
        } else {
          float xl = LP[XLAST_F + b];
          pr += LP[SB_F + 32 + jj] + LP[SB_F + 64 + jj] * xl;
          pz += LP[SB_F + 48 + jj] + LP[SB_F + 80 + jj] * xl;
          pni = PR[(0 * 32 + 16 + jj) * 17 + b] + PR[(2 * 32 + 16 + jj) * 17 + b]
              + LP[SB_F + 128 + jj] + LP[SB_F + 144 + jj] * xl;
        }
        float rg = 1.f / (1.f + expf(-pr));
        float zg = 1.f / (1.f + expf(-pz));
        float ng = tanhf(fmaf(rg, pnh, pni));
        float hv = fmaf(zg, hpreg - ng, ng);
        // reconstruct own published value (same arithmetic consumers see)
        unsigned h0h = rne16(hv);
        float r0 = hv - __uint_as_float(h0h << 16);
        unsigned l0w = rne16(r0);
        hpreg = __uint_as_float(h0h << 16) + __uint_as_float(l0w << 16);
        float hvp = __shfl_xor(hv, 16, 64);   // partner jj^1, same batch
        if ((jj & 1) == 0) {
          unsigned h1h = rne16(hvp);
          float r1 = hvp - __uint_as_float(h1h << 16);
          unsigned hw = h0h | (h1h << 16);
          unsigned lw = l0w | (rne16(r1) << 16);
          const int cc = (2 * s + (jj >> 3)) & 3;
          const int e = jj & 7;
          size_t hoff = (size_t)ks0 * 1024 + (size_t)(b | (cc << 4)) * 16 + (size_t)e * 2;
          char* dst = data + (size_t)(hist ? (t + 1) : ((t + 1) & 1)) * STEP_BYTES
                    + (size_t)g * GRP_BYTES;
          unsigned* dhh = (unsigned*)(dst + hoff);
          unsigned* dhl = (unsigned*)(dst + 16384 + hoff);
          if (mode == 2) {
            *(volatile unsigned*)dhh = hw;
            *(volatile unsigned*)dhl = lw;
          } else {
            __hip_atomic_store(dhh, hw, __ATOMIC_RELAXED, __HIP_MEMORY_SCOPE_AGENT);
            __hip_atomic_store(dhl, lw, __ATOMIC_RELAXED, __HIP_MEMORY_SCOPE_AGENT);
          }
        }
      }
      // -------- drain, arrive, hidden work; next iteration polls per-wave --------
      asm volatile("s_waitcnt vmcnt(0)" ::: "memory");
      __syncthreads();   // sync C: all publishes complete group-visible
      const unsigned tgt = (unsigned)(t + 2);
      if (tid == 0) flag_put(tgt);
      if (t >= 1 && tid >= 256 && tid < 288) {
        const int q = tid - 256, b = q & 15, d = q >> 4;
        float o = LP[SB_F + 160 + d];
#pragma unroll
        for (int i = 0; i < 16; ++i) o += LP[ORED_F + d * 272 + b * 17 + i];
        out[((size_t)(bg0 + b) * 512 + (t - 1)) * 64 + 2 * s + d] = o;
      }
      stage_x(t + 1);
    } else {
      if (tid >= 256 && tid < 288) {
        const int q = tid - 256, b = q & 15, d = q >> 4;
        float o = LP[SB_F + 160 + d];
#pragma unroll
        for (int i = 0; i < 16; ++i) o += LP[ORED_F + d * 272 + b * 17 + i];
        out[((size_t)(bg0 + b) * 512 + 511) * 64 + 2 * s + d] = o;
      }
    }
  }
}

extern "C" void kernel_launch(void* const* d_in, const int* in_sizes, int n_in,
                              void* d_out, int out_size, void* d_ws, size_t ws_size,
                              hipStream_t stream) {
  (void)in_sizes; (void)n_in; (void)out_size;
  const float* x    = (const float*)d_in[0];
  const float* tp   = (const float*)d_in[1];
  const int*   mask = (const int*)d_in[2];
  const float* W_ih = (const float*)d_in[3];
  const float* W_hh = (const float*)d_in[4];
  const float* b_ih = (const float*)d_in[5];
  const float* b_hh = (const float*)d_in[6];
  const float* W_out= (const float*)d_in[7];
  const float* b_out= (const float*)d_in[8];
  float* out = (float*)d_out;
  if (ws_size < FB_NEEDED) return;
  int hist = (ws_size >= HIST_NEEDED) ? 1 : 0;
  hipMemsetAsync(d_ws, 0, CTRL_BYTES, stream);
  hipFuncSetAttribute((const void*)gru_persistent,
                      hipFuncAttributeMaxDynamicSharedMemorySize, LDS_BYTES);
  hipLaunchKernelGGL(gru_persistent, dim3(NWG), dim3(TB), LDS_BYTES, stream,
                     x, tp, mask, W_ih, W_hh, b_ih, b_hh, W_out, b_out,
                     (char*)d_ws, out, hist);
}

// Round 14
// 3248.768 us; speedup vs baseline: 1.6111x; 1.1050x over previous
//
#include <hip/hip_runtime.h>
#include <math.h>

// B=128, T=512, D=64, H=512. 256 WGs = 32 dim-slices (16 dims each) x 8 batch-groups (16 batches).
// 1 WG/CU. Round-13 structure with ROUND-14 changes:
//  - mode 1 fabric only (proven r5/r6): publishes = sc1 agent stores -> LLC; flag polls = PLAIN
//    agent loads (pipelined, no RMW serialization); h fetch = plain cached loads of write-once
//    hist buffers (group = blockIdx&7 = XCD under round-robin dispatch -> L2 read dedup free).
//  - busy-wait polls (no s_sleep) to avoid DVFS downclock inflating chain latency.
//  - registration/mode-2 machinery removed.
// Step skeleton (3 syncs): per-wave poll(4 producers)+stage 4KB -> syncA -> MFMA/out-dot ->
// syncB -> gates(hpreg)+publish -> drain -> syncC -> arrive -> hidden(out-write, stage_x).
#define TB 512
#define NWG 256
#define NSL 32

typedef __attribute__((ext_vector_type(8))) short bf16x8;
typedef __attribute__((ext_vector_type(4))) float f32x4;
typedef unsigned long long u64;

// LDS float offsets. Bytes [0,32768) = staged h image (and B-build scratch at init).
#define PREP_F 8192      // [2kh][2slot][32 rows][17] = 2176
#define XPRE_F 10368     // 48 x 17 = 816 (teacher x-dot r16,z16,n16)
#define ORED_F 11184     // 2 x 16 x 17 = 544 (out partials, 2 dims)
#define WOC_F  11728     // 2 x 512 (W_out cols 2s, 2s+1)
#define WIH_F  12752     // 48 x 66 = 3168
#define SB_F   15920     // 176 biases ([160..161]=b_out)
#define XLAST_F 16096    // 16
#define MSK_F  16112     // 512 ints
#define LDS_FLOATS 16640
#define LDS_BYTES (LDS_FLOATS * 4)   // 66560

#define FLAG_STRIDE 32               // one flag word per 128B line
#define FLAGS_BYTES (NWG * 128)      // 32KB
#define CTRL_BYTES (FLAGS_BYTES + 4096)
#define GRP_BYTES 32768
#define STEP_BYTES (8 * GRP_BYTES)
#define DATA_OFF CTRL_BYTES
#define HIST_NEEDED ((unsigned long long)DATA_OFF + 513ull * STEP_BYTES)
#define FB_NEEDED   ((unsigned long long)DATA_OFF + 2ull * STEP_BYTES)

__device__ __forceinline__ unsigned rne16(float f) {
  unsigned u = __float_as_uint(f);
  return (u + 0x7FFFu + ((u >> 16) & 1u)) >> 16;
}
__device__ __forceinline__ float bfhilo(unsigned hh, unsigned hl) {
  return __uint_as_float(hh << 16) + __uint_as_float(hl << 16);
}

__global__ __launch_bounds__(TB, 2) void gru_persistent(
    const float* __restrict__ x, const float* __restrict__ tp, const int* __restrict__ mask,
    const float* __restrict__ W_ih, const float* __restrict__ W_hh,
    const float* __restrict__ b_ih, const float* __restrict__ b_hh,
    const float* __restrict__ W_out, const float* __restrict__ b_out,
    char* __restrict__ ws, float* __restrict__ out, int hist)
{
  extern __shared__ char smem[];
  float* LP = (float*)smem;
  int* MSK = (int*)&LP[MSK_F];
  const int tid = threadIdx.x;
  const int lane = tid & 63;
  const int wv   = tid >> 6;
  const int myct = wv >> 1, mykh = wv & 1;

  unsigned* flags = (unsigned*)ws;
  char* data = ws + DATA_OFF;

  const int g = blockIdx.x & 7;   // == XCD under round-robin dispatch (locality bonus, not correctness)
  const int s = blockIdx.x >> 3;  // 0..31
  const int bg0 = g * 16;
  const int j0  = 16 * s;
  const int ks0 = s >> 1;
  const int c0  = (2 * s) & 3, c1 = (2 * s + 1) & 3;

  // ---------------- init staging ----------------
  MSK[tid] = mask[tid];
  if (tid < 65) {
    for (int p = 0; p < 48; ++p) {
      int row = (p < 16) ? (j0 + p) : (p < 32) ? (512 + j0 + (p - 16)) : (1024 + j0 + (p - 32));
      LP[WIH_F + p * 66 + tid] = W_ih[(size_t)row * 65 + tid];
    }
  }
  LP[WOC_F + tid]       = W_out[(size_t)tid * 64 + 2 * s];
  LP[WOC_F + 512 + tid] = W_out[(size_t)tid * 64 + 2 * s + 1];
  if (tid < 48) {
    int row = (tid < 16) ? (j0 + tid) : (tid < 32) ? (512 + j0 + (tid - 16)) : (1024 + j0 + (tid - 32));
    const float* wi = W_ih + (size_t)row * 65;
    float bp = 0.f;
    for (int d = 0; d < 64; ++d) bp = fmaf(wi[d], b_out[d], bp);
    if (tid < 32) {
      float bt = b_ih[row] + b_hh[row];
      LP[SB_F + tid]      = bt;        // teacher rz bias
      LP[SB_F + 32 + tid] = bt + bp;   // AR rz bias
      LP[SB_F + 64 + tid] = wi[64];    // xlast coef rz
    } else {
      int jj = tid - 32;
      LP[SB_F + 96 + jj]  = b_hh[row];       // nh bias
      LP[SB_F + 112 + jj] = b_ih[row];       // ni teacher
      LP[SB_F + 128 + jj] = b_ih[row] + bp;  // ni AR
      LP[SB_F + 144 + jj] = wi[64];          // xlast coef n
    }
  } else if (tid < 50) {
    LP[SB_F + 160 + (tid - 48)] = b_out[2 * s + (tid - 48)];
  }
  __syncthreads();

  // ---------------- build B-frags to registers: 3 ct x 2 col-halves via 32KB scratch ----------
  bf16x8 Bh[16], Bl[16];
  {
    unsigned short* bw16 = (unsigned short*)smem;
#pragma unroll
    for (int ct = 0; ct < 3; ++ct) {
#pragma unroll
      for (int hc = 0; hc < 2; ++hc) {
        const int k = tid;
        const float* wo = W_out + (size_t)k * 64;
        for (int c16 = 0; c16 < 16; ++c16) {
          const int col = hc * 16 + c16;
          float w;
          if (ct == 0) {
            if (col < 16) w = W_hh[(size_t)(1024 + j0 + col) * 512 + k];   // nh
            else {                                                          // ni: Wc only
              const float* wrp = &LP[WIH_F + (32 + col - 16) * 66];
              float a = 0.f;
#pragma unroll 8
              for (int d = 0; d < 64; ++d) a = fmaf(wrp[d], wo[d], a);
              w = a;
            }
          } else if (ct == 1) {
            int row = (col < 16) ? (j0 + col) : (512 + j0 + col - 16);
            w = W_hh[(size_t)row * 512 + k];
          } else {
            int row = (col < 16) ? (j0 + col) : (512 + j0 + col - 16);
            const float* wrp = &LP[WIH_F + col * 66];   // r rows 0-15, z rows 16-31
            float a = 0.f;
#pragma unroll 8
            for (int d = 0; d < 64; ++d) a = fmaf(wrp[d], wo[d], a);
            w = a + W_hh[(size_t)row * 512 + k];
          }
          unsigned wh_ = rne16(w);
          float resid = w - __uint_as_float(wh_ << 16);
          unsigned wl_ = rne16(resid);
          int base = (k >> 5) * 1024 + (c16 | (((k >> 3) & 3) << 4)) * 16 + (k & 7) * 2;
          bw16[base >> 1] = (unsigned short)wh_;
          bw16[(base + 16384) >> 1] = (unsigned short)wl_;
        }
        __syncthreads();
        if (wv < 6 && myct == ct) {
#pragma unroll
          for (int i = 0; i < 8; ++i) {
            Bh[hc * 8 + i] = *(const bf16x8*)(smem + (mykh * 8 + i) * 1024 + lane * 16);
            Bl[hc * 8 + i] = *(const bf16x8*)(smem + 16384 + (mykh * 8 + i) * 1024 + lane * 16);
          }
        }
        __syncthreads();
      }
    }
  }

  // ---------------- zero h0 (buffer 0): this WG's publish region ----------------
  if (tid < 32) {
    const int b = tid & 15, term = tid >> 4;
    char* dst = data + (size_t)g * GRP_BYTES + (size_t)(term * 16 + ks0) * 1024;
    u64* p0 = (u64*)(dst + (size_t)(b | (c0 << 4)) * 16);
    u64* p1 = (u64*)(dst + (size_t)(b | (c1 << 4)) * 16);
    __hip_atomic_store(p0,     0ull, __ATOMIC_RELAXED, __HIP_MEMORY_SCOPE_AGENT);
    __hip_atomic_store(p0 + 1, 0ull, __ATOMIC_RELAXED, __HIP_MEMORY_SCOPE_AGENT);
    __hip_atomic_store(p1,     0ull, __ATOMIC_RELAXED, __HIP_MEMORY_SCOPE_AGENT);
    __hip_atomic_store(p1 + 1, 0ull, __ATOMIC_RELAXED, __HIP_MEMORY_SCOPE_AGENT);
  }

  // teacher x-dot staging for step tt (h-independent; runs in hidden windows)
  auto stage_x = [&](int tt) {
    if (tt >= 512) return;
    if (MSK[tt] != 0) {
      for (int task = tid; task < 768; task += TB) {
        const int xr = task >> 4, b = task & 15;
        const float* wrow = &LP[WIH_F + xr * 66];
        size_t ti = (size_t)(bg0 + b) * 512 + tt;
        float del = tp[ti] - (tt > 0 ? tp[ti - 1] : 0.f);
        float xa = wrow[64] * del;
        const float4* x4 = (const float4*)(x + ti * 64);
#pragma unroll
        for (int d4 = 0; d4 < 16; ++d4) {
          float4 xv = x4[d4];
          xa = fmaf(wrow[d4 * 4 + 0], xv.x, xa);
          xa = fmaf(wrow[d4 * 4 + 1], xv.y, xa);
          xa = fmaf(wrow[d4 * 4 + 2], xv.z, xa);
          xa = fmaf(wrow[d4 * 4 + 3], xv.w, xa);
        }
        LP[XPRE_F + xr * 17 + b] = xa;
      }
    } else if (tid < 16) {
      LP[XLAST_F + tid] = x[((size_t)(bg0 + tid) * 512 + tt) * 64 + 63];
    }
  };

  auto flag_addr = [&](int i) -> unsigned* { return &flags[(size_t)((g << 5) + i) * FLAG_STRIDE]; };
  auto flag_put = [&](unsigned tgt_epoch) {
    __hip_atomic_store(flag_addr(s), tgt_epoch, __ATOMIC_RELAXED, __HIP_MEMORY_SCOPE_AGENT);
  };
  // Per-wave poll of THIS WAVE's 4 producers (lanes 0-3, per-lane exit, BUSY SPIN — plain
  // agent loads pipeline at the LLC, no RMW serialization), then stage this wave's 4 chunks.
  auto wave_poll_stage = [&](int tt) {
    const unsigned tgt = (unsigned)(tt + 1);
    if (lane < 4) {
      const int prod = ((lane >> 1) << 4) + 2 * wv + (lane & 1);
      int cnt = 0;
      while (__hip_atomic_load(flag_addr(prod), __ATOMIC_RELAXED, __HIP_MEMORY_SCOPE_AGENT) < tgt) {
        if (++cnt > 2000000) break;   // escape hatch: wrong answer instead of hang
      }
    }
    const char* src = data + (size_t)(hist ? tt : (tt & 1)) * STEP_BYTES + (size_t)g * GRP_BYTES;
    if (hist) {
      uint4 v[4];
#pragma unroll
      for (int i = 0; i < 4; ++i)
        v[i] = *(const uint4*)(src + (size_t)((i * 8 + wv) * 1024) + lane * 16);
#pragma unroll
      for (int i = 0; i < 4; ++i)
        *(uint4*)(smem + (size_t)((i * 8 + wv) * 1024) + lane * 16) = v[i];
    } else {
      u64 a0[4], a1[4];
#pragma unroll
      for (int i = 0; i < 4; ++i) {
        const u64* p = (const u64*)(src + (size_t)((i * 8 + wv) * 1024) + lane * 16);
        a0[i] = __hip_atomic_load(p,     __ATOMIC_RELAXED, __HIP_MEMORY_SCOPE_AGENT);
        a1[i] = __hip_atomic_load(p + 1, __ATOMIC_RELAXED, __HIP_MEMORY_SCOPE_AGENT);
      }
#pragma unroll
      for (int i = 0; i < 4; ++i) {
        u64* d = (u64*)(smem + (size_t)((i * 8 + wv) * 1024) + lane * 16);
        d[0] = a0[i]; d[1] = a1[i];
      }
    }
  };

  stage_x(0);
  asm volatile("s_waitcnt vmcnt(0)" ::: "memory");
  __syncthreads();
  if (tid == 0) flag_put(1u);

  float hpreg = 0.f;   // gate threads: own h(t) value (identical-arithmetic reconstruction)

  for (int t = 0; t <= 512; ++t) {
    const bool last = (t == 512);
    const bool teacher = (!last) && (MSK[t] != 0);
    const int csel = teacher ? 1 : 2;

    // -------- per-wave: poll my 4 producers for h(t), stage my 4KB of the image --------
    wave_poll_stage(t);
    __syncthreads();   // sync A: full image staged

    // -------- MFMA (waves 0-5): ct0 always, ct1 teacher, ct2 AR; 2 col-tiles each --------
    if (!last && wv < 6 && (myct == 0 || myct == csel)) {
      const int slot = (myct == 0) ? 0 : 1;
#pragma unroll
      for (int ti = 0; ti < 2; ++ti) {
        f32x4 acc0 = {0.f, 0.f, 0.f, 0.f};
        f32x4 acc1 = {0.f, 0.f, 0.f, 0.f};
        f32x4 acc2 = {0.f, 0.f, 0.f, 0.f};
        f32x4 acc3 = {0.f, 0.f, 0.f, 0.f};
#pragma unroll
        for (int i = 0; i < 8; ++i) {
          const char* abh = smem + (size_t)((mykh * 8 + i) * 1024) + lane * 16;
          bf16x8 ahh = *(const bf16x8*)abh;
          bf16x8 ahl = *(const bf16x8*)(abh + 16384);
          f32x4& acc = ((i & 3) == 0) ? acc0 : ((i & 3) == 1) ? acc1 : ((i & 3) == 2) ? acc2 : acc3;
          acc = __builtin_amdgcn_mfma_f32_16x16x32_bf16(ahh, Bh[ti * 8 + i], acc, 0, 0, 0);
          acc = __builtin_amdgcn_mfma_f32_16x16x32_bf16(ahh, Bl[ti * 8 + i], acc, 0, 0, 0);
          acc = __builtin_amdgcn_mfma_f32_16x16x32_bf16(ahl, Bh[ti * 8 + i], acc, 0, 0, 0);
        }
        f32x4 acc = (acc0 + acc1) + (acc2 + acc3);
        const int row = ti * 16 + (lane & 15);
        const int bcol = (lane >> 4) << 2;
#pragma unroll
        for (int q = 0; q < 4; ++q)
          LP[PREP_F + ((mykh * 2 + slot) * 32 + row) * 17 + bcol + q] = acc[q];
      }
    }

    // -------- out-dot (waves 6,7): 512 tasks = 2 dims x 16 b x 16 ks, 4/thread --------
    if (wv >= 6) {
#pragma unroll
      for (int tk = 0; tk < 4; ++tk) {
        const int task = (tid - 384) + tk * 128;
        const int d = task >> 8, rem = task & 255;
        const int b = rem & 15, ks = rem >> 4;
        const float* woc = &LP[WOC_F + d * 512];
        float oa = 0.f;
#pragma unroll
        for (int c = 0; c < 4; ++c) {
          const uint4 wh = *(const uint4*)(smem + (size_t)(ks * 1024) + (b | (c << 4)) * 16);
          const uint4 wl = *(const uint4*)(smem + (size_t)(16384 + ks * 1024) + (b | (c << 4)) * 16);
          int k0 = ks * 32 + c * 8;
          oa = fmaf(bfhilo(wh.x & 0xFFFFu, wl.x & 0xFFFFu), woc[k0 + 0], oa);
          oa = fmaf(bfhilo(wh.x >> 16, wl.x >> 16), woc[k0 + 1], oa);
          oa = fmaf(bfhilo(wh.y & 0xFFFFu, wl.y & 0xFFFFu), woc[k0 + 2], oa);
          oa = fmaf(bfhilo(wh.y >> 16, wl.y >> 16), woc[k0 + 3], oa);
          oa = fmaf(bfhilo(wh.z & 0xFFFFu, wl.z & 0xFFFFu), woc[k0 + 4], oa);
          oa = fmaf(bfhilo(wh.z >> 16, wl.z >> 16), woc[k0 + 5], oa);
          oa = fmaf(bfhilo(wh.w & 0xFFFFu, wl.w & 0xFFFFu), woc[k0 + 6], oa);
          oa = fmaf(bfhilo(wh.w >> 16, wl.w >> 16), woc[k0 + 7], oa);
        }
        LP[ORED_F + d * 272 + b * 17 + ks] = oa;
      }
    }
    __syncthreads();   // sync B

    if (!last) {
      // -------- gates (tid<256: b=tid&15, jj=tid>>4) -> shfl pack -> publish --------
      if (tid < 256) {
        const int b = tid & 15, jj = tid >> 4;
        const float* PR = &LP[PREP_F];
        float pr  = PR[(1 * 32 + jj) * 17 + b]      + PR[(3 * 32 + jj) * 17 + b];
        float pz  = PR[(1 * 32 + 16 + jj) * 17 + b] + PR[(3 * 32 + 16 + jj) * 17 + b];
        float pnh = PR[(0 * 32 + jj) * 17 + b]      + PR[(2 * 32 + jj) * 17 + b]
                  + LP[SB_F + 96 + jj];
        float pni;
        if (teacher) {
          pr += LP[XPRE_F + jj * 17 + b] + LP[SB_F + jj];
          pz += LP[XPRE_F + (16 + jj) * 17 + b] + LP[SB_F + 16 + jj];
          pni = LP[XPRE_F + (32 + jj) * 17 + b] + LP[SB_F + 112 + jj];
        } else {
          float xl = LP[XLAST_F + b];
          pr += LP[SB_F + 32 + jj] + LP[SB_F + 64 + jj] * xl;
          pz += LP[SB_F + 48 + jj] + LP[SB_F + 80 + jj] * xl;
          pni = PR[(0 * 32 + 16 + jj) * 17 + b] + PR[(2 * 32 + 16 + jj) * 17 + b]
              + LP[SB_F + 128 + jj] + LP[SB_F + 144 + jj] * xl;
        }
        float rg = 1.f / (1.f + expf(-pr));
        float zg = 1.f / (1.f + expf(-pz));
        float ng = tanhf(fmaf(rg, pnh, pni));
        float hv = fmaf(zg, hpreg - ng, ng);
        // reconstruct own published value (same arithmetic consumers see)
        unsigned h0h = rne16(hv);
        float r0 = hv - __uint_as_float(h0h << 16);
        unsigned l0w = rne16(r0);
        hpreg = __uint_as_float(h0h << 16) + __uint_as_float(l0w << 16);
        float hvp = __shfl_xor(hv, 16, 64);   // partner jj^1, same batch
        if ((jj & 1) == 0) {
          unsigned h1h = rne16(hvp);
          float r1 = hvp - __uint_as_float(h1h << 16);
          unsigned hw = h0h | (h1h << 16);
          unsigned lw = l0w | (rne16(r1) << 16);
          const int cc = (2 * s + (jj >> 3)) & 3;
          const int e = jj & 7;
          size_t hoff = (size_t)ks0 * 1024 + (size_t)(b | (cc << 4)) * 16 + (size_t)e * 2;
          char* dst = data + (size_t)(hist ? (t + 1) : ((t + 1) & 1)) * STEP_BYTES
                    + (size_t)g * GRP_BYTES;
          unsigned* dhh = (unsigned*)(dst + hoff);
          unsigned* dhl = (unsigned*)(dst + 16384 + hoff);
          __hip_atomic_store(dhh, hw, __ATOMIC_RELAXED, __HIP_MEMORY_SCOPE_AGENT);
          __hip_atomic_store(dhl, lw, __ATOMIC_RELAXED, __HIP_MEMORY_SCOPE_AGENT);
        }
      }
      // -------- drain, arrive, hidden work; next iteration polls per-wave --------
      asm volatile("s_waitcnt vmcnt(0)" ::: "memory");
      __syncthreads();   // sync C: all publishes at coherence point
      const unsigned tgt = (unsigned)(t + 2);
      if (tid == 0) flag_put(tgt);
      if (t >= 1 && tid >= 256 && tid < 288) {
        const int q = tid - 256, b = q & 15, d = q >> 4;
        float o = LP[SB_F + 160 + d];
#pragma unroll
        for (int i = 0; i < 16; ++i) o += LP[ORED_F + d * 272 + b * 17 + i];
        out[((size_t)(bg0 + b) * 512 + (t - 1)) * 64 + 2 * s + d] = o;
      }
      stage_x(t + 1);
    } else {
      if (tid >= 256 && tid < 288) {
        const int q = tid - 256, b = q & 15, d = q >> 4;
        float o = LP[SB_F + 160 + d];
#pragma unroll
        for (int i = 0; i < 16; ++i) o += LP[ORED_F + d * 272 + b * 17 + i];
        out[((size_t)(bg0 + b) * 512 + 511) * 64 + 2 * s + d] = o;
      }
    }
  }
}

extern "C" void kernel_launch(void* const* d_in, const int* in_sizes, int n_in,
                              void* d_out, int out_size, void* d_ws, size_t ws_size,
                              hipStream_t stream) {
  (void)in_sizes; (void)n_in; (void)out_size;
  const float* x    = (const float*)d_in[0];
  const float* tp   = (const float*)d_in[1];
  const int*   mask = (const int*)d_in[2];
  const float* W_ih = (const float*)d_in[3];
  const float* W_hh = (const float*)d_in[4];
  const float* b_ih = (const float*)d_in[5];
  const float* b_hh = (const float*)d_in[6];
  const float* W_out= (const float*)d_in[7];
  const float* b_out= (const float*)d_in[8];
  float* out = (float*)d_out;
  if (ws_size < FB_NEEDED) return;
  int hist = (ws_size >= HIST_NEEDED) ? 1 : 0;
  hipMemsetAsync(d_ws, 0, CTRL_BYTES, stream);
  hipFuncSetAttribute((const void*)gru_persistent,
                      hipFuncAttributeMaxDynamicSharedMemorySize, LDS_BYTES);
  hipLaunchKernelGGL(gru_persistent, dim3(NWG), dim3(TB), LDS_BYTES, stream,
                     x, tp, mask, W_ih, W_hh, b_ih, b_hh, W_out, b_out,
                     (char*)d_ws, out, hist);
}

// Round 15
// 3107.022 us; speedup vs baseline: 1.6846x; 1.0456x over previous
//
#include <hip/hip_runtime.h>
#include <math.h>

// B=128, T=512, D=64, H=512. 256 WGs = 32 dim-slices (16 dims each) x 8 batch-groups (16 batches).
// 1 WG/CU. Round-14 skeleton (mode-1 LLC fabric, busy polls, per-wave aligned poll+stage, hpreg).
// ROUND-15: out-projection h@W_out computed by MFMA on waves 6-7 (B = W_out cols hi/lo, zero-padded
// to 16 cols) instead of the VALU out-dot (640 serial ops) — cuts the syncB critical path.
// Gate-MFMA loops restructured i-outer so each A-frag is ds_read once (16 reads/wave).
#define TB 512
#define NWG 256
#define NSL 32

typedef __attribute__((ext_vector_type(8))) short bf16x8;
typedef __attribute__((ext_vector_type(4))) float f32x4;
typedef unsigned long long u64;

// LDS float offsets. Bytes [0,32768) = staged h image (and B-build scratch at init).
#define PREP_F 8192      // [2kh][2slot][32 rows][17] = 2176
#define XPRE_F 10368     // 48 x 17 = 816 (teacher x-dot r16,z16,n16)
#define OPART_F 11184    // [2kh x 2d][17] = 68 (out partials via MFMA)
#define WIH_F  12752     // 48 x 66 = 3168
#define SB_F   15920     // 176 biases ([160..161]=b_out)
#define XLAST_F 16096    // 16
#define MSK_F  16112     // 512 ints
#define LDS_FLOATS 16640
#define LDS_BYTES (LDS_FLOATS * 4)   // 66560

#define FLAG_STRIDE 32               // one flag word per 128B line
#define FLAGS_BYTES (NWG * 128)      // 32KB
#define CTRL_BYTES (FLAGS_BYTES + 4096)
#define GRP_BYTES 32768
#define STEP_BYTES (8 * GRP_BYTES)
#define DATA_OFF CTRL_BYTES
#define HIST_NEEDED ((unsigned long long)DATA_OFF + 513ull * STEP_BYTES)
#define FB_NEEDED   ((unsigned long long)DATA_OFF + 2ull * STEP_BYTES)

__device__ __forceinline__ unsigned rne16(float f) {
  unsigned u = __float_as_uint(f);
  return (u + 0x7FFFu + ((u >> 16) & 1u)) >> 16;
}

__global__ __launch_bounds__(TB, 2) void gru_persistent(
    const float* __restrict__ x, const float* __restrict__ tp, const int* __restrict__ mask,
    const float* __restrict__ W_ih, const float* __restrict__ W_hh,
    const float* __restrict__ b_ih, const float* __restrict__ b_hh,
    const float* __restrict__ W_out, const float* __restrict__ b_out,
    char* __restrict__ ws, float* __restrict__ out, int hist)
{
  extern __shared__ char smem[];
  float* LP = (float*)smem;
  int* MSK = (int*)&LP[MSK_F];
  const int tid = threadIdx.x;
  const int lane = tid & 63;
  const int wv   = tid >> 6;
  const int myct = wv >> 1, mykh = wv & 1;

  unsigned* flags = (unsigned*)ws;
  char* data = ws + DATA_OFF;

  const int g = blockIdx.x & 7;   // == XCD under round-robin dispatch (locality bonus only)
  const int s = blockIdx.x >> 3;  // 0..31
  const int bg0 = g * 16;
  const int j0  = 16 * s;
  const int ks0 = s >> 1;
  const int c0  = (2 * s) & 3, c1 = (2 * s + 1) & 3;

  // ---------------- init staging ----------------
  MSK[tid] = mask[tid];
  if (tid < 65) {
    for (int p = 0; p < 48; ++p) {
      int row = (p < 16) ? (j0 + p) : (p < 32) ? (512 + j0 + (p - 16)) : (1024 + j0 + (p - 32));
      LP[WIH_F + p * 66 + tid] = W_ih[(size_t)row * 65 + tid];
    }
  }
  if (tid < 48) {
    int row = (tid < 16) ? (j0 + tid) : (tid < 32) ? (512 + j0 + (tid - 16)) : (1024 + j0 + (tid - 32));
    const float* wi = W_ih + (size_t)row * 65;
    float bp = 0.f;
    for (int d = 0; d < 64; ++d) bp = fmaf(wi[d], b_out[d], bp);
    if (tid < 32) {
      float bt = b_ih[row] + b_hh[row];
      LP[SB_F + tid]      = bt;        // teacher rz bias
      LP[SB_F + 32 + tid] = bt + bp;   // AR rz bias
      LP[SB_F + 64 + tid] = wi[64];    // xlast coef rz
    } else {
      int jj = tid - 32;
      LP[SB_F + 96 + jj]  = b_hh[row];       // nh bias
      LP[SB_F + 112 + jj] = b_ih[row];       // ni teacher
      LP[SB_F + 128 + jj] = b_ih[row] + bp;  // ni AR
      LP[SB_F + 144 + jj] = wi[64];          // xlast coef n
    }
  } else if (tid < 50) {
    LP[SB_F + 160 + (tid - 48)] = b_out[2 * s + (tid - 48)];
  }
  __syncthreads();

  // ---------------- build B-frags to registers ----------------
  bf16x8 Bh[16], Bl[16];   // gate weights: 3ct x 2 col-halves (waves 0-5)
  bf16x8 Boh[8], Bol[8];   // W_out cols (waves 6-7)
  {
    unsigned short* bw16 = (unsigned short*)smem;
#pragma unroll
    for (int ct = 0; ct < 3; ++ct) {
#pragma unroll
      for (int hc = 0; hc < 2; ++hc) {
        const int k = tid;
        const float* wo = W_out + (size_t)k * 64;
        for (int c16 = 0; c16 < 16; ++c16) {
          const int col = hc * 16 + c16;
          float w;
          if (ct == 0) {
            if (col < 16) w = W_hh[(size_t)(1024 + j0 + col) * 512 + k];   // nh
            else {                                                          // ni: Wc only
              const float* wrp = &LP[WIH_F + (32 + col - 16) * 66];
              float a = 0.f;
#pragma unroll 8
              for (int d = 0; d < 64; ++d) a = fmaf(wrp[d], wo[d], a);
              w = a;
            }
          } else if (ct == 1) {
            int row = (col < 16) ? (j0 + col) : (512 + j0 + col - 16);
            w = W_hh[(size_t)row * 512 + k];
          } else {
            int row = (col < 16) ? (j0 + col) : (512 + j0 + col - 16);
            const float* wrp = &LP[WIH_F + col * 66];   // r rows 0-15, z rows 16-31
            float a = 0.f;
#pragma unroll 8
            for (int d = 0; d < 64; ++d) a = fmaf(wrp[d], wo[d], a);
            w = a + W_hh[(size_t)row * 512 + k];
          }
          unsigned wh_ = rne16(w);
          float resid = w - __uint_as_float(wh_ << 16);
          unsigned wl_ = rne16(resid);
          int base = (k >> 5) * 1024 + (c16 | (((k >> 3) & 3) << 4)) * 16 + (k & 7) * 2;
          bw16[base >> 1] = (unsigned short)wh_;
          bw16[(base + 16384) >> 1] = (unsigned short)wl_;
        }
        __syncthreads();
        if (wv < 6 && myct == ct) {
#pragma unroll
          for (int i = 0; i < 8; ++i) {
            Bh[hc * 8 + i] = *(const bf16x8*)(smem + (mykh * 8 + i) * 1024 + lane * 16);
            Bl[hc * 8 + i] = *(const bf16x8*)(smem + 16384 + (mykh * 8 + i) * 1024 + lane * 16);
          }
        }
        __syncthreads();
      }
    }
    // Bo pass: W_out cols 2s,2s+1 (hi/lo), cols 2..15 zero
    {
      const int k = tid;
      for (int c16 = 0; c16 < 16; ++c16) {
        float w = (c16 < 2) ? W_out[(size_t)k * 64 + 2 * s + c16] : 0.f;
        unsigned wh_ = rne16(w);
        float resid = w - __uint_as_float(wh_ << 16);
        unsigned wl_ = rne16(resid);
        int base = (k >> 5) * 1024 + (c16 | (((k >> 3) & 3) << 4)) * 16 + (k & 7) * 2;
        bw16[base >> 1] = (unsigned short)wh_;
        bw16[(base + 16384) >> 1] = (unsigned short)wl_;
      }
      __syncthreads();
      if (wv >= 6) {
#pragma unroll
        for (int i = 0; i < 8; ++i) {
          Boh[i] = *(const bf16x8*)(smem + (mykh * 8 + i) * 1024 + lane * 16);
          Bol[i] = *(const bf16x8*)(smem + 16384 + (mykh * 8 + i) * 1024 + lane * 16);
        }
      }
      __syncthreads();
    }
  }

  // ---------------- zero h0 (buffer 0): this WG's publish region ----------------
  if (tid < 32) {
    const int b = tid & 15, term = tid >> 4;
    char* dst = data + (size_t)g * GRP_BYTES + (size_t)(term * 16 + ks0) * 1024;
    u64* p0 = (u64*)(dst + (size_t)(b | (c0 << 4)) * 16);
    u64* p1 = (u64*)(dst + (size_t)(b | (c1 << 4)) * 16);
    __hip_atomic_store(p0,     0ull, __ATOMIC_RELAXED, __HIP_MEMORY_SCOPE_AGENT);
    __hip_atomic_store(p0 + 1, 0ull, __ATOMIC_RELAXED, __HIP_MEMORY_SCOPE_AGENT);
    __hip_atomic_store(p1,     0ull, __ATOMIC_RELAXED, __HIP_MEMORY_SCOPE_AGENT);
    __hip_atomic_store(p1 + 1, 0ull, __ATOMIC_RELAXED, __HIP_MEMORY_SCOPE_AGENT);
  }

  // teacher x-dot staging for step tt (h-independent; runs in hidden windows)
  auto stage_x = [&](int tt) {
    if (tt >= 512) return;
    if (MSK[tt] != 0) {
      for (int task = tid; task < 768; task += TB) {
        const int xr = task >> 4, b = task & 15;
        const float* wrow = &LP[WIH_F + xr * 66];
        size_t ti = (size_t)(bg0 + b) * 512 + tt;
        float del = tp[ti] - (tt > 0 ? tp[ti - 1] : 0.f);
        float xa = wrow[64] * del;
        const float4* x4 = (const float4*)(x + ti * 64);
#pragma unroll
        for (int d4 = 0; d4 < 16; ++d4) {
          float4 xv = x4[d4];
          xa = fmaf(wrow[d4 * 4 + 0], xv.x, xa);
          xa = fmaf(wrow[d4 * 4 + 1], xv.y, xa);
          xa = fmaf(wrow[d4 * 4 + 2], xv.z, xa);
          xa = fmaf(wrow[d4 * 4 + 3], xv.w, xa);
        }
        LP[XPRE_F + xr * 17 + b] = xa;
      }
    } else if (tid < 16) {
      LP[XLAST_F + tid] = x[((size_t)(bg0 + tid) * 512 + tt) * 64 + 63];
    }
  };

  auto flag_addr = [&](int i) -> unsigned* { return &flags[(size_t)((g << 5) + i) * FLAG_STRIDE]; };
  auto flag_put = [&](unsigned tgt_epoch) {
    __hip_atomic_store(flag_addr(s), tgt_epoch, __ATOMIC_RELAXED, __HIP_MEMORY_SCOPE_AGENT);
  };
  // Per-wave poll of this wave's 4 producers (lanes 0-3, busy spin), then stage its 4KB.
  auto wave_poll_stage = [&](int tt) {
    const unsigned tgt = (unsigned)(tt + 1);
    if (lane < 4) {
      const int prod = ((lane >> 1) << 4) + 2 * wv + (lane & 1);
      int cnt = 0;
      while (__hip_atomic_load(flag_addr(prod), __ATOMIC_RELAXED, __HIP_MEMORY_SCOPE_AGENT) < tgt) {
        if (++cnt > 2000000) break;   // escape hatch: wrong answer instead of hang
      }
    }
    const char* src = data + (size_t)(hist ? tt : (tt & 1)) * STEP_BYTES + (size_t)g * GRP_BYTES;
    if (hist) {
      uint4 v[4];
#pragma unroll
      for (int i = 0; i < 4; ++i)
        v[i] = *(const uint4*)(src + (size_t)((i * 8 + wv) * 1024) + lane * 16);
#pragma unroll
      for (int i = 0; i < 4; ++i)
        *(uint4*)(smem + (size_t)((i * 8 + wv) * 1024) + lane * 16) = v[i];
    } else {
      u64 a0[4], a1[4];
#pragma unroll
      for (int i = 0; i < 4; ++i) {
        const u64* p = (const u64*)(src + (size_t)((i * 8 + wv) * 1024) + lane * 16);
        a0[i] = __hip_atomic_load(p,     __ATOMIC_RELAXED, __HIP_MEMORY_SCOPE_AGENT);
        a1[i] = __hip_atomic_load(p + 1, __ATOMIC_RELAXED, __HIP_MEMORY_SCOPE_AGENT);
      }
#pragma unroll
      for (int i = 0; i < 4; ++i) {
        u64* d = (u64*)(smem + (size_t)((i * 8 + wv) * 1024) + lane * 16);
        d[0] = a0[i]; d[1] = a1[i];
      }
    }
  };

  stage_x(0);
  asm volatile("s_waitcnt vmcnt(0)" ::: "memory");
  __syncthreads();
  if (tid == 0) flag_put(1u);

  float hpreg = 0.f;   // gate threads: own h(t) value (identical-arithmetic reconstruction)

  for (int t = 0; t <= 512; ++t) {
    const bool last = (t == 512);
    const bool teacher = (!last) && (MSK[t] != 0);
    const int csel = teacher ? 1 : 2;

    // -------- per-wave: poll my 4 producers for h(t), stage my 4KB of the image --------
    wave_poll_stage(t);
    __syncthreads();   // sync A: full image staged

    // -------- gate MFMA (waves 0-5): i-outer, both col-tiles per A-read --------
    if (!last && wv < 6 && (myct == 0 || myct == csel)) {
      const int slot = (myct == 0) ? 0 : 1;
      f32x4 aA0 = {0.f,0.f,0.f,0.f}, aA1 = aA0, aA2 = aA0, aA3 = aA0;
      f32x4 aB0 = aA0, aB1 = aA0, aB2 = aA0, aB3 = aA0;
#pragma unroll
      for (int i = 0; i < 8; ++i) {
        const char* abh = smem + (size_t)((mykh * 8 + i) * 1024) + lane * 16;
        bf16x8 ahh = *(const bf16x8*)abh;
        bf16x8 ahl = *(const bf16x8*)(abh + 16384);
        f32x4& a0 = ((i & 3) == 0) ? aA0 : ((i & 3) == 1) ? aA1 : ((i & 3) == 2) ? aA2 : aA3;
        a0 = __builtin_amdgcn_mfma_f32_16x16x32_bf16(ahh, Bh[i], a0, 0, 0, 0);
        a0 = __builtin_amdgcn_mfma_f32_16x16x32_bf16(ahh, Bl[i], a0, 0, 0, 0);
        a0 = __builtin_amdgcn_mfma_f32_16x16x32_bf16(ahl, Bh[i], a0, 0, 0, 0);
        f32x4& a1 = ((i & 3) == 0) ? aB0 : ((i & 3) == 1) ? aB1 : ((i & 3) == 2) ? aB2 : aB3;
        a1 = __builtin_amdgcn_mfma_f32_16x16x32_bf16(ahh, Bh[8 + i], a1, 0, 0, 0);
        a1 = __builtin_amdgcn_mfma_f32_16x16x32_bf16(ahh, Bl[8 + i], a1, 0, 0, 0);
        a1 = __builtin_amdgcn_mfma_f32_16x16x32_bf16(ahl, Bh[8 + i], a1, 0, 0, 0);
      }
      f32x4 accA = (aA0 + aA1) + (aA2 + aA3);
      f32x4 accB = (aB0 + aB1) + (aB2 + aB3);
      const int r0_ = lane & 15;
      const int bcol = (lane >> 4) << 2;
#pragma unroll
      for (int q = 0; q < 4; ++q) {
        LP[PREP_F + ((mykh * 2 + slot) * 32 + r0_) * 17 + bcol + q]      = accA[q];
        LP[PREP_F + ((mykh * 2 + slot) * 32 + 16 + r0_) * 17 + bcol + q] = accB[q];
      }
    }

    // -------- out MFMA (waves 6,7): D col = out-dim (2 useful), row = batch --------
    if (wv >= 6) {   // runs at t==512 too (row 511)
      f32x4 o0 = {0.f,0.f,0.f,0.f}, o1 = o0, o2 = o0, o3 = o0;
#pragma unroll
      for (int i = 0; i < 8; ++i) {
        const char* abh = smem + (size_t)((mykh * 8 + i) * 1024) + lane * 16;
        bf16x8 ahh = *(const bf16x8*)abh;
        bf16x8 ahl = *(const bf16x8*)(abh + 16384);
        f32x4& oc = ((i & 3) == 0) ? o0 : ((i & 3) == 1) ? o1 : ((i & 3) == 2) ? o2 : o3;
        oc = __builtin_amdgcn_mfma_f32_16x16x32_bf16(ahh, Boh[i], oc, 0, 0, 0);
        oc = __builtin_amdgcn_mfma_f32_16x16x32_bf16(ahh, Bol[i], oc, 0, 0, 0);
        oc = __builtin_amdgcn_mfma_f32_16x16x32_bf16(ahl, Boh[i], oc, 0, 0, 0);
      }
      f32x4 oacc = (o0 + o1) + (o2 + o3);
      if ((lane & 15) < 2) {
#pragma unroll
        for (int q = 0; q < 4; ++q)
          LP[OPART_F + (mykh * 2 + (lane & 15)) * 17 + ((lane >> 4) * 4 + q)] = oacc[q];
      }
    }
    __syncthreads();   // sync B

    if (!last) {
      // -------- gates (tid<256: b=tid&15, jj=tid>>4) -> shfl pack -> publish --------
      if (tid < 256) {
        const int b = tid & 15, jj = tid >> 4;
        const float* PR = &LP[PREP_F];
        float pr  = PR[(1 * 32 + jj) * 17 + b]      + PR[(3 * 32 + jj) * 17 + b];
        float pz  = PR[(1 * 32 + 16 + jj) * 17 + b] + PR[(3 * 32 + 16 + jj) * 17 + b];
        float pnh = PR[(0 * 32 + jj) * 17 + b]      + PR[(2 * 32 + jj) * 17 + b]
                  + LP[SB_F + 96 + jj];
        float pni;
        if (teacher) {
          pr += LP[XPRE_F + jj * 17 + b] + LP[SB_F + jj];
          pz += LP[XPRE_F + (16 + jj) * 17 + b] + LP[SB_F + 16 + jj];
          pni = LP[XPRE_F + (32 + jj) * 17 + b] + LP[SB_F + 112 + jj];
        } else {
          float xl = LP[XLAST_F + b];
          pr += LP[SB_F + 32 + jj] + LP[SB_F + 64 + jj] * xl;
          pz += LP[SB_F + 48 + jj] + LP[SB_F + 80 + jj] * xl;
          pni = PR[(0 * 32 + 16 + jj) * 17 + b] + PR[(2 * 32 + 16 + jj) * 17 + b]
              + LP[SB_F + 128 + jj] + LP[SB_F + 144 + jj] * xl;
        }
        float rg = 1.f / (1.f + expf(-pr));
        float zg = 1.f / (1.f + expf(-pz));
        float ng = tanhf(fmaf(rg, pnh, pni));
        float hv = fmaf(zg, hpreg - ng, ng);
        // reconstruct own published value (same arithmetic consumers see)
        unsigned h0h = rne16(hv);
        float r0 = hv - __uint_as_float(h0h << 16);
        unsigned l0w = rne16(r0);
        hpreg = __uint_as_float(h0h << 16) + __uint_as_float(l0w << 16);
        float hvp = __shfl_xor(hv, 16, 64);   // partner jj^1, same batch
        if ((jj & 1) == 0) {
          unsigned h1h = rne16(hvp);
          float r1 = hvp - __uint_as_float(h1h << 16);
          unsigned hw = h0h | (h1h << 16);
          unsigned lw = l0w | (rne16(r1) << 16);
          const int cc = (2 * s + (jj >> 3)) & 3;
          const int e = jj & 7;
          size_t hoff = (size_t)ks0 * 1024 + (size_t)(b | (cc << 4)) * 16 + (size_t)e * 2;
          char* dst = data + (size_t)(hist ? (t + 1) : ((t + 1) & 1)) * STEP_BYTES
                    + (size_t)g * GRP_BYTES;
          unsigned* dhh = (unsigned*)(dst + hoff);
          unsigned* dhl = (unsigned*)(dst + 16384 + hoff);
          __hip_atomic_store(dhh, hw, __ATOMIC_RELAXED, __HIP_MEMORY_SCOPE_AGENT);
          __hip_atomic_store(dhl, lw, __ATOMIC_RELAXED, __HIP_MEMORY_SCOPE_AGENT);
        }
      }
      // -------- drain, arrive, hidden work; next iteration polls per-wave --------
      asm volatile("s_waitcnt vmcnt(0)" ::: "memory");
      __syncthreads();   // sync C: all publishes at coherence point
      const unsigned tgt = (unsigned)(t + 2);
      if (tid == 0) flag_put(tgt);
      if (t >= 1 && tid >= 256 && tid < 288) {
        const int q = tid - 256, b = q & 15, d = q >> 4;
        float o = LP[SB_F + 160 + d] + LP[OPART_F + d * 17 + b] + LP[OPART_F + (2 + d) * 17 + b];
        out[((size_t)(bg0 + b) * 512 + (t - 1)) * 64 + 2 * s + d] = o;
      }
      stage_x(t + 1);
    } else {
      if (tid >= 256 && tid < 288) {
        const int q = tid - 256, b = q & 15, d = q >> 4;
        float o = LP[SB_F + 160 + d] + LP[OPART_F + d * 17 + b] + LP[OPART_F + (2 + d) * 17 + b];
        out[((size_t)(bg0 + b) * 512 + 511) * 64 + 2 * s + d] = o;
      }
    }
  }
}

extern "C" void kernel_launch(void* const* d_in, const int* in_sizes, int n_in,
                              void* d_out, int out_size, void* d_ws, size_t ws_size,
                              hipStream_t stream) {
  (void)in_sizes; (void)n_in; (void)out_size;
  const float* x    = (const float*)d_in[0];
  const float* tp   = (const float*)d_in[1];
  const int*   mask = (const int*)d_in[2];
  const float* W_ih = (const float*)d_in[3];
  const float* W_hh = (const float*)d_in[4];
  const float* b_ih = (const float*)d_in[5];
  const float* b_hh = (const float*)d_in[6];
  const float* W_out= (const float*)d_in[7];
  const float* b_out= (const float*)d_in[8];
  float* out = (float*)d_out;
  if (ws_size < FB_NEEDED) return;
  int hist = (ws_size >= HIST_NEEDED) ? 1 : 0;
  hipMemsetAsync(d_ws, 0, CTRL_BYTES, stream);
  hipFuncSetAttribute((const void*)gru_persistent,
                      hipFuncAttributeMaxDynamicSharedMemorySize, LDS_BYTES);
  hipLaunchKernelGGL(gru_persistent, dim3(NWG), dim3(TB), LDS_BYTES, stream,
                     x, tp, mask, W_ih, W_hh, b_ih, b_hh, W_out, b_out,
                     (char*)d_ws, out, hist);
}